// Round 15
// baseline (48.512 us; speedup 1.0000x reference)
//
#include <hip/hip_runtime.h>
#include <math.h>

#pragma clang fp contract(off)

#define HH 384
#define WW 640
#define HW (HH * WW)
#define NBOX 32
#define NSORT 8192       // conceptual zero-padded array (>= max rect 82*62, > max k)
#define NTHR 256         // phase2 block size
#define P1THR 256        // phase1 block size (4 waves)

// Bit-exact shared IoU: both phases must produce identical f32 values,
// since phase-1's threshold is compared strictly against phase-2's iou.
__device__ __forceinline__ float iou_at(float p0, float p1, float p2, float p3,
                                        float rx, float ry,
                                        float bcx, float bcy, float bw, float bh) {
#pragma clang fp contract(off)
    float x1 = p0 * 80.0f + rx;
    float y1 = p1 * 80.0f + ry;
    float x2 = p2 * 80.0f + rx;
    float y2 = p3 * 80.0f + ry;
    float wp = x2 - x1;
    float hp = y2 - y1;
    float cxp = x1 + wp * 0.5f;
    float cyp = y1 + hp * 0.5f;
    float pminx = cxp - wp * 0.5f;
    float pminy = cyp - hp * 0.5f;
    float pmaxx = cxp + wp * 0.5f;
    float pmaxy = cyp + hp * 0.5f;
    float bminx = bcx - bw * 0.5f;
    float bminy = bcy - bh * 0.5f;
    float bmaxx = bcx + bw * 0.5f;
    float bmaxy = bcy + bh * 0.5f;
    float iminx = fmaxf(pminx, bminx);
    float iminy = fmaxf(pminy, bminy);
    float imaxx = fminf(pmaxx, bmaxx);
    float imaxy = fminf(pmaxy, bmaxy);
    float iw = fmaxf(imaxx - iminx, 0.0f);
    float ih = fmaxf(imaxy - iminy, 0.0f);
    float inter = iw * ih;
    float uni = wp * hp + bw * bh - inter;
    uni = fmaxf(uni, 1e-6f);
    return inter / uni;
}

// Phase 1 (R15): 256 thr = 4 waves per (image, box). 3x8 supertiles of 32x8
// threads (24 static slots). 5 barriers total: the per-pass selection scan is
// done REDUNDANTLY by every wave (identical integer result) with in-wave
// ballot+shfl broadcast, eliminating the 2nd barrier of each radix pass.
__global__ __launch_bounds__(P1THR) void phase1(const float* __restrict__ pb,
                                                const float* __restrict__ bboxes,
                                                unsigned* __restrict__ ws) {
#pragma clang fp contract(off)
    int pair = blockIdx.x;          // 0..511
    int img = pair >> 5;
    int tid = threadIdx.x;
    int wid = tid >> 6;             // 0..3
    int lane = tid & 63;
    int tx = tid & 31;              // col-in-tile
    int ty = tid >> 5;              // row-in-tile 0..7

    __shared__ unsigned hall[19 * 256];   // [0..15]: pass-3 sub-hists; [16..18]: passes 2..0
#define H3(g, b)   hall[(g) * 256 + (b)]
#define HLOW(p, b) hall[16 * 256 + (p) * 256 + (b)]
    __shared__ double wsum[4];
    __shared__ int wnz[4];

    const float* b = bboxes + (size_t)pair * 6;
    float bx1 = b[0], by1 = b[1], bx2 = b[2], by2 = b[3];
    float extra = b[5];
    float bw = bx2 - bx1;
    float bh = by2 - by1;
    float bcx = bx1 + bw * 0.5f;
    float bcy = by1 + bh * 0.5f;
    bool valid = (bw * bh) > 0.0f;

    float aw = ((bcx - bw * 0.5f) * 640.0f) / 1280.0f - 0.5f;
    float zw = ((bcx + bw * 0.5f) * 640.0f) / 1280.0f - 0.5f;
    float ah = ((bcy - bh * 0.5f) * 384.0f) / 768.0f - 0.5f;
    float zh = ((bcy + bh * 0.5f) * 384.0f) / 768.0f - 0.5f;
    int miw = (int)floorf(fmaxf(aw, 0.0f));
    int maw = (int)ceilf(fminf(zw, 639.0f));
    int mih = (int)floorf(fmaxf(ah, 0.0f));
    int mah = (int)ceilf(fminf(zh, 383.0f));
    if (!valid) { miw = 0; maw = -1; mih = 0; mah = -1; }

    int rw = maw - miw + 1;                 // <= 82
    int rh = mah - mih + 1;                 // <= 62
    bool hasR = (rw > 0 && rh > 0);
    int tilesC = hasR ? ((rw + 31) >> 5) : 0;   // <= 3
    int tilesR = hasR ? ((rh + 7) >> 3) : 0;    // <= 8

    for (int i = tid; i < 19 * 256; i += P1THR) hall[i] = 0u;

    // 24 static slots (3 col-tiles x 8 row-tiles of 32x8 threads).
    const float* base = pb + (size_t)img * 4 * HW;
    unsigned v[24];
    double lsum = 0.0;
    int nz = 0;
#pragma unroll
    for (int tc = 0; tc < 3; ++tc) {
#pragma unroll
        for (int tr = 0; tr < 8; ++tr) {
            unsigned u = 0u;
            int cc = miw + tc * 32 + tx;
            int rr = mih + tr * 8 + ty;
            bool ok = (tc < tilesC) && (tr < tilesR) && (cc <= maw) && (rr <= mah);
            if (ok) {
                int off = rr * WW + cc;
                float p0 = base[off];
                float p1 = base[HW + off];
                float p2 = base[2 * HW + off];
                float p3 = base[3 * HW + off];
                float iou = iou_at(p0, p1, p2, p3,
                                   (float)(2 * cc + 1), (float)(2 * rr + 1),
                                   bcx, bcy, bw, bh);
                u = __float_as_uint(iou);   // iou >= 0: uint order == float order
                lsum += (double)iou;
                nz += (u != 0u) ? 1 : 0;
            }
            v[tc * 8 + tr] = u;             // static index
        }
    }

    // wave butterfly reduce (lockstep), 4 partials to LDS, barrier 1
    for (int off = 1; off < 64; off <<= 1) {
        lsum += __shfl_xor(lsum, off);
        nz += __shfl_xor(nz, off);
    }
    if (lane == 0) { wsum[wid] = lsum; wnz[wid] = nz; }
    __syncthreads();

    double s = wsum[0] + wsum[1] + wsum[2] + wsum[3];
    int nztot = wnz[0] + wnz[1] + wnz[2] + wnz[3];
    double sm = s > 1.0 ? s : 1.0;
    int k = (int)ceil(sm);
    unsigned rank = (unsigned)k;            // 0-based rank in descending order
    unsigned pref = 0u;
    unsigned padT = (unsigned)(NSORT - nztot);
    int subh = tid >> 4;                    // 16-way sub-hist split for pass 3

    // 4-pass radix select; ONE barrier per pass. Every wave redundantly
    // scans the finalized histogram (identical integer result); in-wave
    // ballot+shfl broadcasts the selected bin. Pass p-1's atomics target a
    // different (pre-zeroed) buffer than pass p's scan reads -> no hazard.
#pragma unroll
    for (int p = 3; p >= 0; --p) {
        unsigned mask = (p == 3) ? 0u : (0xFFFFFFFFu << ((p + 1) * 8));
#pragma unroll
        for (int j = 0; j < 24; ++j) {
            unsigned u = v[j];
            if (u != 0u && (u & mask) == pref) {
                unsigned bn = (u >> (p * 8)) & 255;
                if (p == 3) atomicAdd(&H3(subh, bn), 1u);
                else        atomicAdd(&HLOW(p, bn), 1u);
            }
        }
        __syncthreads();                    // hist(p) final; barriers 2..5
        // all-wave redundant scan: lane owns bins 4l..4l+3
        uint4 hq;
        if (p == 3) {
            hq = make_uint4(0u, 0u, 0u, 0u);
#pragma unroll
            for (int g = 0; g < 16; ++g) {
                uint4 t = *(const uint4*)&H3(g, 4 * lane);
                hq.x += t.x; hq.y += t.y; hq.z += t.z; hq.w += t.w;
            }
        } else {
            hq = *(const uint4*)&HLOW(p, 4 * lane);
        }
        if (lane == 0 && pref == 0u) hq.x += padT;
        unsigned s3 = hq.w;
        unsigned s2 = hq.z + s3;
        unsigned s1 = hq.y + s2;
        unsigned s0 = hq.x + s1;
        unsigned T = s0;
        for (int off = 1; off < 64; off <<= 1) {
            unsigned t = __shfl_down(T, off);
            if (lane + off < 64) T += t;
        }
        unsigned above = T - s0;            // elems in bins above this lane's 4
        unsigned G0 = s0 + above;
        unsigned G1 = s1 + above;
        unsigned G2 = s2 + above;
        unsigned G3 = s3 + above;
        int selb = -1; unsigned nr = 0;
        if (rank < G0 && rank >= G1)      { selb = 0; nr = rank - G1; }
        else if (rank < G1 && rank >= G2) { selb = 1; nr = rank - G2; }
        else if (rank < G2 && rank >= G3) { selb = 2; nr = rank - G3; }
        else if (rank < G3 && rank >= above) { selb = 3; nr = rank - above; }
        unsigned cand_pref = pref | ((unsigned)(4 * lane + (selb < 0 ? 0 : selb)) << (p * 8));
        unsigned long long bal = __ballot(selb >= 0);   // exactly one lane/wave
        int src = (int)__builtin_ctzll(bal);
        pref = __shfl(cand_pref, src);
        rank = __shfl(nr, src);
    }

    if (tid == 0) {
        float thresh = __uint_as_float(pref);
        float lam = 1.0f / sqrtf((float)k);
        unsigned* rec = ws + (size_t)pair * 16;
        rec[0] = (unsigned)miw;
        rec[1] = (unsigned)maw;
        rec[2] = (unsigned)mih;
        rec[3] = (unsigned)mah;
        rec[4] = __float_as_uint(bcx);
        rec[5] = __float_as_uint(bcy);
        rec[6] = __float_as_uint(bw);
        rec[7] = __float_as_uint(bh);
        rec[8] = __float_as_uint(extra);
        rec[9] = __float_as_uint(lam);
        rec[10] = __float_as_uint(thresh);
    }
#undef H3
#undef HLOW
}

// Phase 2: byte-identical to R14 (rowmask + predicated loads + LDS-staged
// coalesced stream-out).
__global__ __launch_bounds__(NTHR) void phase2(const float* __restrict__ pb,
                                               const unsigned* __restrict__ ws,
                                               float* __restrict__ out) {
#pragma clang fp contract(off)
    int tid = threadIdx.x;
    const int bpi = HW / (NTHR * 4);        // 240 blocks per image
    int img = blockIdx.x / bpi;
    int px0blk = (blockIdx.x - img * bpi) * (NTHR * 4);
    int px0 = px0blk + tid * 4;

    __shared__ unsigned rec[NBOX * 16];
    __shared__ float lpts[NTHR * 24];       // 24 KB tile in output layout
    __shared__ unsigned rowm[3];            // box masks for the tile's <=3 rows
    for (int i = tid; i < NBOX * 16; i += NTHR)
        rec[i] = ws[(size_t)img * NBOX * 16 + i];
    __syncthreads();

    int row = px0 / WW;                      // 640 % 4 == 0: no row straddle per thread
    int col0 = px0 - row * WW;
    int r0 = px0blk / WW;                    // tile spans rows r0..r0+2

    if (tid < 64) {                          // wave 0: 3 ballots build row masks
        int b = tid & 31;
        const unsigned* r = rec + b * 16;
        int mih = (int)r[2], mah = (int)r[3];
#pragma unroll
        for (int i = 0; i < 3; ++i) {
            int rr = r0 + i;
            bool hit = (tid < 32) && (rr >= mih) && (rr <= mah);
            unsigned long long bal = __ballot(hit);
            if (tid == 0) rowm[i] = (unsigned)bal;   // low 32 bits = boxes 0..31
        }
    }
    __syncthreads();

    unsigned hm = 0u;
    {
        unsigned mm = rowm[row - r0];
        while (mm) {
            int b = __builtin_ctz(mm);
            mm &= mm - 1u;
            const unsigned* r = rec + b * 16;
            if (col0 + 3 >= (int)r[0] && col0 <= (int)r[1])
                hm |= 1u << b;
        }
    }
    unsigned wm = hm;                        // wave-OR (lockstep butterfly)
    for (int off = 1; off < 64; off <<= 1)
        wm |= __shfl_xor(wm, off);

    float cls0[4] = {1.f, 1.f, 1.f, 1.f};
    float cls1[4] = {0.f, 0.f, 0.f, 0.f};
    float pt[4][6];
#pragma unroll
    for (int p2 = 0; p2 < 4; ++p2)
#pragma unroll
        for (int q = 0; q < 6; ++q) pt[p2][q] = 1.0f;

    if (wm != 0u) {                          // wave-uniform branch
        const float* base = pb + (size_t)img * 4 * HW;
        float4 q0 = make_float4(0.f, 0.f, 0.f, 0.f);
        float4 q1 = q0, q2 = q0, q3 = q0;
        if (hm != 0u) {                      // per-thread predicated loads
            q0 = *(const float4*)(base + px0);
            q1 = *(const float4*)(base + HW + px0);
            q2 = *(const float4*)(base + 2 * HW + px0);
            q3 = *(const float4*)(base + 3 * HW + px0);
        }
        float ry = (float)(2 * row + 1);
        float best[4] = {0.f, 0.f, 0.f, 0.f};

        unsigned m = wm;
        while (m) {                          // ascending bb == reference order
            int bb2 = __builtin_ctz(m);
            m &= m - 1u;
            if ((hm >> bb2) & 1u) {
                const unsigned* r = rec + bb2 * 16;
                int miw = (int)r[0];
                int maw = (int)r[1];
                float bcx = __uint_as_float(r[4]);
                float bcy = __uint_as_float(r[5]);
                float bw = __uint_as_float(r[6]);
                float bh = __uint_as_float(r[7]);
                float ext = __uint_as_float(r[8]);
                float lam = __uint_as_float(r[9]);
                float thr = __uint_as_float(r[10]);
#pragma unroll
                for (int p2 = 0; p2 < 4; ++p2) {
                    int col = col0 + p2;
                    if (col < miw || col > maw) continue;
                    float pp0 = (p2 == 0) ? q0.x : (p2 == 1) ? q0.y : (p2 == 2) ? q0.z : q0.w;
                    float pp1 = (p2 == 0) ? q1.x : (p2 == 1) ? q1.y : (p2 == 2) ? q1.z : q1.w;
                    float pp2 = (p2 == 0) ? q2.x : (p2 == 1) ? q2.y : (p2 == 2) ? q2.z : q2.w;
                    float pp3 = (p2 == 0) ? q3.x : (p2 == 1) ? q3.y : (p2 == 2) ? q3.z : q3.w;
                    float iou = iou_at(pp0, pp1, pp2, pp3,
                                       (float)(2 * col + 1), ry, bcx, bcy, bw, bh);
                    float iou_k = (iou > thr) ? iou : 0.0f;
                    if (iou_k > 0.0f) {
                        if (iou_k > best[p2]) {
                            cls0[p2] = 0.0f; cls1[p2] = 1.0f;
                            pt[p2][0] = bcx; pt[p2][1] = bcy;
                            pt[p2][2] = bw;  pt[p2][3] = bh;
                            pt[p2][4] = ext; pt[p2][5] = lam;
                            best[p2] = iou_k;
                        } else if (iou_k == best[p2] && best[p2] > 0.0f) {
                            cls0[p2] = 0.0f; cls1[p2] = 0.0f;
                        }
                    } else {
                        cls0[p2] = 0.0f;
                    }
                }
            }
        }
    }

    // stage pts tile in LDS (uniform barrier), then coalesced float4 stream-out
#pragma unroll
    for (int p2 = 0; p2 < 4; ++p2) {
        float4* lp = (float4*)&lpts[(tid * 4 + p2) * 6];
        lp[0] = make_float4(pt[p2][0], pt[p2][1], pt[p2][2], pt[p2][3]);
        lpts[(tid * 4 + p2) * 6 + 4] = pt[p2][4];
        lpts[(tid * 4 + p2) * 6 + 5] = pt[p2][5];
    }
    __syncthreads();
    {
        const float4* lp4 = (const float4*)lpts;
        float4* gp4 = (float4*)(out + (size_t)16 * HW * 2 +
                                ((size_t)img * HW + px0blk) * 6);
#pragma unroll
        for (int kk = 0; kk < 6; ++kk)
            gp4[tid + kk * NTHR] = lp4[tid + kk * NTHR];
    }

    // cls: 2 float4 per thread, stride-32B (each 64B line fully covered)
    float* cb = out + ((size_t)img * HW + px0) * 2;
    ((float4*)cb)[0] = make_float4(cls0[0], cls1[0], cls0[1], cls1[1]);
    ((float4*)cb)[1] = make_float4(cls0[2], cls1[2], cls0[3], cls1[3]);
}

extern "C" void kernel_launch(void* const* d_in, const int* in_sizes, int n_in,
                              void* d_out, int out_size, void* d_ws, size_t ws_size,
                              hipStream_t stream) {
    (void)in_sizes; (void)n_in; (void)out_size; (void)ws_size;
    const float* pb = (const float*)d_in[1];   // pred_boxes (16,4,384,640)
    const float* bb = (const float*)d_in[2];   // bboxes (16,32,6)
    unsigned* ws = (unsigned*)d_ws;            // 512 * 16 u32 records
    float* out = (float*)d_out;

    phase1<<<dim3(16 * NBOX), dim3(P1THR), 0, stream>>>(pb, bb, ws);
    phase2<<<dim3(16 * (HW / (NTHR * 4))), dim3(NTHR), 0, stream>>>(pb, ws, out);
}

// Round 16
// 42.720 us; speedup vs baseline: 1.1356x; 1.1356x over previous
//
#include <hip/hip_runtime.h>
#include <math.h>

#pragma clang fp contract(off)

#define HH 384
#define WW 640
#define HW (HH * WW)
#define NBOX 32
#define NSORT 8192       // conceptual zero-padded array (>= max rect 82*62, > max k)
#define NTHR 256         // phase2 block size
#define P1THR 512        // phase1 block size (8 waves)

// Bit-exact shared IoU: both phases must produce identical f32 values,
// since phase-1's threshold is compared strictly against phase-2's iou.
__device__ __forceinline__ float iou_at(float p0, float p1, float p2, float p3,
                                        float rx, float ry,
                                        float bcx, float bcy, float bw, float bh) {
#pragma clang fp contract(off)
    float x1 = p0 * 80.0f + rx;
    float y1 = p1 * 80.0f + ry;
    float x2 = p2 * 80.0f + rx;
    float y2 = p3 * 80.0f + ry;
    float wp = x2 - x1;
    float hp = y2 - y1;
    float cxp = x1 + wp * 0.5f;
    float cyp = y1 + hp * 0.5f;
    float pminx = cxp - wp * 0.5f;
    float pminy = cyp - hp * 0.5f;
    float pmaxx = cxp + wp * 0.5f;
    float pmaxy = cyp + hp * 0.5f;
    float bminx = bcx - bw * 0.5f;
    float bminy = bcy - bh * 0.5f;
    float bmaxx = bcx + bw * 0.5f;
    float bmaxy = bcy + bh * 0.5f;
    float iminx = fmaxf(pminx, bminx);
    float iminy = fmaxf(pminy, bminy);
    float imaxx = fminf(pmaxx, bmaxx);
    float imaxy = fminf(pmaxy, bmaxy);
    float iw = fmaxf(imaxx - iminx, 0.0f);
    float ih = fmaxf(imaxy - iminy, 0.0f);
    float inter = iw * ih;
    float uni = wp * hp + bw * bh - inter;
    uni = fmaxf(uni, 1e-6f);
    return inter / uni;
}

// Phase 1: one block (512 thr = 8 waves) per (image, box). Measured ~10.3 us
// (R9 double-launch). Byte-identical to R8/R11/R14 — both restructure
// attempts (256-thr/24-slot, redundant-scan) regressed; this shape is the
// local optimum.
__global__ __launch_bounds__(P1THR) void phase1(const float* __restrict__ pb,
                                                const float* __restrict__ bboxes,
                                                unsigned* __restrict__ ws) {
#pragma clang fp contract(off)
    int pair = blockIdx.x;          // 0..511
    int img = pair >> 5;
    int box = pair & 31;
    int tid = threadIdx.x;
    int wid = tid >> 6;             // 0..7
    int lane = tid & 63;
    int tx = tid & 31;              // col-in-tile
    int ty = tid >> 5;              // row-in-tile 0..15

    __shared__ unsigned hall[19 * 256];   // [0..15]: pass-3 sub-hists; [16..18]: passes 2..0
#define H3(g, b)   hall[(g) * 256 + (b)]
#define HLOW(p, b) hall[16 * 256 + (p) * 256 + (b)]
    __shared__ double wsum[8];
    __shared__ int wnz[8];
    __shared__ unsigned sel_prefix_s;
    __shared__ unsigned sel_rank_s;

    const float* b = bboxes + (size_t)(img * NBOX + box) * 6;
    float bx1 = b[0], by1 = b[1], bx2 = b[2], by2 = b[3];
    float extra = b[5];
    float bw = bx2 - bx1;
    float bh = by2 - by1;
    float bcx = bx1 + bw * 0.5f;
    float bcy = by1 + bh * 0.5f;
    bool valid = (bw * bh) > 0.0f;

    float aw = ((bcx - bw * 0.5f) * 640.0f) / 1280.0f - 0.5f;
    float zw = ((bcx + bw * 0.5f) * 640.0f) / 1280.0f - 0.5f;
    float ah = ((bcy - bh * 0.5f) * 384.0f) / 768.0f - 0.5f;
    float zh = ((bcy + bh * 0.5f) * 384.0f) / 768.0f - 0.5f;
    int miw = (int)floorf(fmaxf(aw, 0.0f));
    int maw = (int)ceilf(fminf(zw, 639.0f));
    int mih = (int)floorf(fmaxf(ah, 0.0f));
    int mah = (int)ceilf(fminf(zh, 383.0f));
    if (!valid) { miw = 0; maw = -1; mih = 0; mah = -1; }

    int rw = maw - miw + 1;                 // <= 82
    int rh = mah - mih + 1;                 // <= 62
    bool hasR = (rw > 0 && rh > 0);
    int tilesC = hasR ? ((rw + 31) >> 5) : 0;   // <= 3
    int tilesR = hasR ? ((rh + 15) >> 4) : 0;   // <= 4

    for (int i = tid; i < 19 * 256; i += P1THR) hall[i] = 0u;

    const float* base = pb + (size_t)img * 4 * HW;
    unsigned v[12];
    double lsum = 0.0;
    int nz = 0;
#pragma unroll
    for (int tc = 0; tc < 3; ++tc) {
#pragma unroll
        for (int tr = 0; tr < 4; ++tr) {
            unsigned u = 0u;
            int cc = miw + tc * 32 + tx;
            int rr = mih + tr * 16 + ty;
            bool ok = (tc < tilesC) && (tr < tilesR) && (cc <= maw) && (rr <= mah);
            if (ok) {
                int off = rr * WW + cc;
                float p0 = base[off];
                float p1 = base[HW + off];
                float p2 = base[2 * HW + off];
                float p3 = base[3 * HW + off];
                float iou = iou_at(p0, p1, p2, p3,
                                   (float)(2 * cc + 1), (float)(2 * rr + 1),
                                   bcx, bcy, bw, bh);
                u = __float_as_uint(iou);   // iou >= 0: uint order == float order
                lsum += (double)iou;
                nz += (u != 0u) ? 1 : 0;
            }
            v[tc * 4 + tr] = u;             // static index
        }
    }

    for (int off = 1; off < 64; off <<= 1) {
        lsum += __shfl_xor(lsum, off);
        nz += __shfl_xor(nz, off);
    }
    if (lane == 0) { wsum[wid] = lsum; wnz[wid] = nz; }
    __syncthreads();

    double s = 0.0;
    int nztot = 0;
#pragma unroll
    for (int w = 0; w < 8; ++w) { s += wsum[w]; nztot += wnz[w]; }
    double sm = s > 1.0 ? s : 1.0;
    int k = (int)ceil(sm);
    unsigned rank = (unsigned)k;            // 0-based rank in descending order
    unsigned pref = 0u;
    unsigned padT = (unsigned)(NSORT - nztot);
    int subh = tid >> 5;                    // 16-way sub-hist split for pass 3

#pragma unroll
    for (int p = 3; p >= 0; --p) {
        unsigned mask = (p == 3) ? 0u : (0xFFFFFFFFu << ((p + 1) * 8));
#pragma unroll
        for (int j = 0; j < 12; ++j) {
            unsigned u = v[j];
            if (u != 0u && (u & mask) == pref) {
                unsigned bn = (u >> (p * 8)) & 255;
                if (p == 3) atomicAdd(&H3(subh, bn), 1u);
                else        atomicAdd(&HLOW(p, bn), 1u);
            }
        }
        __syncthreads();
        if (wid == 0) {
            uint4 hq;
            if (p == 3) {
                hq = make_uint4(0u, 0u, 0u, 0u);
#pragma unroll
                for (int g = 0; g < 16; ++g) {
                    uint4 t = *(const uint4*)&H3(g, 4 * lane);
                    hq.x += t.x; hq.y += t.y; hq.z += t.z; hq.w += t.w;
                }
            } else {
                hq = *(const uint4*)&HLOW(p, 4 * lane);
            }
            if (lane == 0 && pref == 0u) hq.x += padT;
            unsigned s3 = hq.w;
            unsigned s2 = hq.z + s3;
            unsigned s1 = hq.y + s2;
            unsigned s0 = hq.x + s1;
            unsigned T = s0;
            for (int off = 1; off < 64; off <<= 1) {
                unsigned t = __shfl_down(T, off);
                if (lane + off < 64) T += t;
            }
            unsigned above = T - s0;
            unsigned G0 = s0 + above;
            unsigned G1 = s1 + above;
            unsigned G2 = s2 + above;
            unsigned G3 = s3 + above;
            int selb = -1; unsigned nr = 0;
            if (rank < G0 && rank >= G1)      { selb = 0; nr = rank - G1; }
            else if (rank < G1 && rank >= G2) { selb = 1; nr = rank - G2; }
            else if (rank < G2 && rank >= G3) { selb = 2; nr = rank - G3; }
            else if (rank < G3 && rank >= above) { selb = 3; nr = rank - above; }
            if (selb >= 0) {
                sel_prefix_s = pref | ((unsigned)(4 * lane + selb) << (p * 8));
                sel_rank_s = nr;
            }
        }
        __syncthreads();
        pref = sel_prefix_s;
        rank = sel_rank_s;
    }

    if (tid == 0) {
        float thresh = __uint_as_float(pref);
        float lam = 1.0f / sqrtf((float)k);
        unsigned* rec = ws + (size_t)pair * 16;
        rec[0] = (unsigned)miw;
        rec[1] = (unsigned)maw;
        rec[2] = (unsigned)mih;
        rec[3] = (unsigned)mah;
        rec[4] = __float_as_uint(bcx);
        rec[5] = __float_as_uint(bcy);
        rec[6] = __float_as_uint(bw);
        rec[7] = __float_as_uint(bh);
        rec[8] = __float_as_uint(extra);
        rec[9] = __float_as_uint(lam);
        rec[10] = __float_as_uint(thresh);
    }
#undef H3
#undef HLOW
}

// Phase 2: byte-identical to R14 (rowmask + predicated loads + LDS-staged
// coalesced stream-out, plain stores).
__global__ __launch_bounds__(NTHR) void phase2(const float* __restrict__ pb,
                                               const unsigned* __restrict__ ws,
                                               float* __restrict__ out) {
#pragma clang fp contract(off)
    int tid = threadIdx.x;
    const int bpi = HW / (NTHR * 4);        // 240 blocks per image
    int img = blockIdx.x / bpi;
    int px0blk = (blockIdx.x - img * bpi) * (NTHR * 4);
    int px0 = px0blk + tid * 4;

    __shared__ unsigned rec[NBOX * 16];
    __shared__ float lpts[NTHR * 24];       // 24 KB tile in output layout
    __shared__ unsigned rowm[3];            // box masks for the tile's <=3 rows
    for (int i = tid; i < NBOX * 16; i += NTHR)
        rec[i] = ws[(size_t)img * NBOX * 16 + i];
    __syncthreads();

    int row = px0 / WW;                      // 640 % 4 == 0: no row straddle per thread
    int col0 = px0 - row * WW;
    int r0 = px0blk / WW;                    // tile spans rows r0..r0+2

    if (tid < 64) {                          // wave 0: 3 ballots build row masks
        int b = tid & 31;
        const unsigned* r = rec + b * 16;
        int mih = (int)r[2], mah = (int)r[3];
#pragma unroll
        for (int i = 0; i < 3; ++i) {
            int rr = r0 + i;
            bool hit = (tid < 32) && (rr >= mih) && (rr <= mah);
            unsigned long long bal = __ballot(hit);
            if (tid == 0) rowm[i] = (unsigned)bal;   // low 32 bits = boxes 0..31
        }
    }
    __syncthreads();

    unsigned hm = 0u;
    {
        unsigned mm = rowm[row - r0];
        while (mm) {
            int b = __builtin_ctz(mm);
            mm &= mm - 1u;
            const unsigned* r = rec + b * 16;
            if (col0 + 3 >= (int)r[0] && col0 <= (int)r[1])
                hm |= 1u << b;
        }
    }
    unsigned wm = hm;                        // wave-OR (lockstep butterfly)
    for (int off = 1; off < 64; off <<= 1)
        wm |= __shfl_xor(wm, off);

    float cls0[4] = {1.f, 1.f, 1.f, 1.f};
    float cls1[4] = {0.f, 0.f, 0.f, 0.f};
    float pt[4][6];
#pragma unroll
    for (int p2 = 0; p2 < 4; ++p2)
#pragma unroll
        for (int q = 0; q < 6; ++q) pt[p2][q] = 1.0f;

    if (wm != 0u) {                          // wave-uniform branch
        const float* base = pb + (size_t)img * 4 * HW;
        float4 q0 = make_float4(0.f, 0.f, 0.f, 0.f);
        float4 q1 = q0, q2 = q0, q3 = q0;
        if (hm != 0u) {                      // per-thread predicated loads
            q0 = *(const float4*)(base + px0);
            q1 = *(const float4*)(base + HW + px0);
            q2 = *(const float4*)(base + 2 * HW + px0);
            q3 = *(const float4*)(base + 3 * HW + px0);
        }
        float ry = (float)(2 * row + 1);
        float best[4] = {0.f, 0.f, 0.f, 0.f};

        unsigned m = wm;
        while (m) {                          // ascending bb == reference order
            int bb2 = __builtin_ctz(m);
            m &= m - 1u;
            if ((hm >> bb2) & 1u) {
                const unsigned* r = rec + bb2 * 16;
                int miw = (int)r[0];
                int maw = (int)r[1];
                float bcx = __uint_as_float(r[4]);
                float bcy = __uint_as_float(r[5]);
                float bw = __uint_as_float(r[6]);
                float bh = __uint_as_float(r[7]);
                float ext = __uint_as_float(r[8]);
                float lam = __uint_as_float(r[9]);
                float thr = __uint_as_float(r[10]);
#pragma unroll
                for (int p2 = 0; p2 < 4; ++p2) {
                    int col = col0 + p2;
                    if (col < miw || col > maw) continue;
                    float pp0 = (p2 == 0) ? q0.x : (p2 == 1) ? q0.y : (p2 == 2) ? q0.z : q0.w;
                    float pp1 = (p2 == 0) ? q1.x : (p2 == 1) ? q1.y : (p2 == 2) ? q1.z : q1.w;
                    float pp2 = (p2 == 0) ? q2.x : (p2 == 1) ? q2.y : (p2 == 2) ? q2.z : q2.w;
                    float pp3 = (p2 == 0) ? q3.x : (p2 == 1) ? q3.y : (p2 == 2) ? q3.z : q3.w;
                    float iou = iou_at(pp0, pp1, pp2, pp3,
                                       (float)(2 * col + 1), ry, bcx, bcy, bw, bh);
                    float iou_k = (iou > thr) ? iou : 0.0f;
                    if (iou_k > 0.0f) {
                        if (iou_k > best[p2]) {
                            cls0[p2] = 0.0f; cls1[p2] = 1.0f;
                            pt[p2][0] = bcx; pt[p2][1] = bcy;
                            pt[p2][2] = bw;  pt[p2][3] = bh;
                            pt[p2][4] = ext; pt[p2][5] = lam;
                            best[p2] = iou_k;
                        } else if (iou_k == best[p2] && best[p2] > 0.0f) {
                            cls0[p2] = 0.0f; cls1[p2] = 0.0f;
                        }
                    } else {
                        cls0[p2] = 0.0f;
                    }
                }
            }
        }
    }

    // stage pts tile in LDS (uniform barrier), then coalesced float4 stream-out
#pragma unroll
    for (int p2 = 0; p2 < 4; ++p2) {
        float4* lp = (float4*)&lpts[(tid * 4 + p2) * 6];
        lp[0] = make_float4(pt[p2][0], pt[p2][1], pt[p2][2], pt[p2][3]);
        lpts[(tid * 4 + p2) * 6 + 4] = pt[p2][4];
        lpts[(tid * 4 + p2) * 6 + 5] = pt[p2][5];
    }
    __syncthreads();
    {
        const float4* lp4 = (const float4*)lpts;
        float4* gp4 = (float4*)(out + (size_t)16 * HW * 2 +
                                ((size_t)img * HW + px0blk) * 6);
#pragma unroll
        for (int kk = 0; kk < 6; ++kk)
            gp4[tid + kk * NTHR] = lp4[tid + kk * NTHR];
    }

    // cls: 2 float4 per thread, stride-32B (each 64B line fully covered)
    float* cb = out + ((size_t)img * HW + px0) * 2;
    ((float4*)cb)[0] = make_float4(cls0[0], cls1[0], cls0[1], cls1[1]);
    ((float4*)cb)[1] = make_float4(cls0[2], cls1[2], cls0[3], cls1[3]);
}

extern "C" void kernel_launch(void* const* d_in, const int* in_sizes, int n_in,
                              void* d_out, int out_size, void* d_ws, size_t ws_size,
                              hipStream_t stream) {
    (void)in_sizes; (void)n_in; (void)out_size; (void)ws_size;
    const float* pb = (const float*)d_in[1];   // pred_boxes (16,4,384,640)
    const float* bb = (const float*)d_in[2];   // bboxes (16,32,6)
    unsigned* ws = (unsigned*)d_ws;            // 512 * 16 u32 records
    float* out = (float*)d_out;

    phase1<<<dim3(16 * NBOX), dim3(P1THR), 0, stream>>>(pb, bb, ws);
    phase2<<<dim3(16 * (HW / (NTHR * 4))), dim3(NTHR), 0, stream>>>(pb, ws, out);
}